// Round 1
// 294.751 us; speedup vs baseline: 1.2870x; 1.2870x over previous
//
#include <hip/hip_runtime.h>
#include <hip/hip_bf16.h>

typedef __hip_bfloat16 bf16;
typedef short v8s __attribute__((ext_vector_type(8)));   // 8 bf16 = 16B (4 VGPRs)
typedef float v4f __attribute__((ext_vector_type(4)));   // MFMA accumulator

#define BB   4
#define NN   1024
#define DD   512
#define NHH  8
#define DH   64

__device__ __forceinline__ void split2(float v, bf16& hi, bf16& lo) {
    hi = __float2bfloat16(v);
    lo = __float2bfloat16(v - __bfloat162float(hi));
}

__device__ __forceinline__ short f2bf_bits(float f) {
    bf16 h = __float2bfloat16(f);
    short s;
    __builtin_memcpy(&s, &h, 2);
    return s;
}

// ---------------------------------------------------------------------------
// K1: LayerNorm (f32 in) -> split bf16 hi/lo out. One block per row, 256 thr.
// ---------------------------------------------------------------------------
__global__ __launch_bounds__(256) void ln_split_kernel(
    const float* __restrict__ x, const float* __restrict__ gamma,
    const float* __restrict__ beta,
    bf16* __restrict__ c_hi, bf16* __restrict__ c_lo)
{
    int row = blockIdx.x;
    int t = threadIdx.x;
    const float* xr = x + (size_t)row * DD;
    float v0 = xr[2 * t];
    float v1 = xr[2 * t + 1];
    float s = v0 + v1;
    float sq = v0 * v0 + v1 * v1;
#pragma unroll
    for (int o = 32; o; o >>= 1) {
        s  += __shfl_down(s, o, 64);
        sq += __shfl_down(sq, o, 64);
    }
    __shared__ float red[8];
    __shared__ float mb[2];
    int wave = t >> 6, lane = t & 63;
    if (lane == 0) { red[wave] = s; red[4 + wave] = sq; }
    __syncthreads();
    if (t == 0) {
        float S  = red[0] + red[1] + red[2] + red[3];
        float SQ = red[4] + red[5] + red[6] + red[7];
        float mean = S * (1.0f / DD);
        float var  = SQ * (1.0f / DD) - mean * mean;
        mb[0] = mean;
        mb[1] = rsqrtf(var + 1e-5f);
    }
    __syncthreads();
    float mean = mb[0], rstd = mb[1];
    float y0 = (v0 - mean) * rstd * gamma[2 * t] + beta[2 * t];
    float y1 = (v1 - mean) * rstd * gamma[2 * t + 1] + beta[2 * t + 1];
    bf16 h, l;
    split2(y0, h, l);
    c_hi[(size_t)row * DD + 2 * t]     = h;
    c_lo[(size_t)row * DD + 2 * t]     = l;
    split2(y1, h, l);
    c_hi[(size_t)row * DD + 2 * t + 1] = h;
    c_lo[(size_t)row * DD + 2 * t + 1] = l;
}

// ---------------------------------------------------------------------------
// K2: dtype conversions. z=0: exo->bf16 (plain, row-major); z=1/2: Wq/Wk ->
// hi/lo REPACKED to [kb][col][32] (kb = d>>5) so proj B-frag loads are a
// single contiguous 1KB wave transaction; z=3: Wv->bf16 same packing.
// ---------------------------------------------------------------------------
__global__ __launch_bounds__(256) void convert_kernel(
    const float* __restrict__ exo, const float* __restrict__ Wq,
    const float* __restrict__ Wk,  const float* __restrict__ Wv,
    bf16* __restrict__ exo_bf,
    bf16* __restrict__ wq_hi, bf16* __restrict__ wq_lo,
    bf16* __restrict__ wk_hi, bf16* __restrict__ wk_lo,
    bf16* __restrict__ wv_bf)
{
    int z = blockIdx.z;
    int n = (z == 0) ? BB * NN * DD : DD * DD;
    int i4 = (blockIdx.x * 256 + threadIdx.x) * 4;
    if (i4 >= n) return;
    const float* src = (z == 0) ? exo : (z == 1) ? Wq : (z == 2) ? Wk : Wv;
    float4 v = *(const float4*)(src + i4);
    float vv[4] = {v.x, v.y, v.z, v.w};
    if (z == 0) {
#pragma unroll
        for (int j = 0; j < 4; ++j) exo_bf[i4 + j] = __float2bfloat16(vv[j]);
        return;
    }
    int col = i4 >> 9;          // W row-major [col][d]
    int d   = i4 & (DD - 1);    // 4 consecutive d stay within one 32-block
    size_t base = ((size_t)(d >> 5) * DD + col) * 32 + (d & 31);
    if (z == 3) {
#pragma unroll
        for (int j = 0; j < 4; ++j) wv_bf[base + j] = __float2bfloat16(vv[j]);
    } else {
        bf16* dh = (z == 1) ? wq_hi : wk_hi;
        bf16* dl = (z == 1) ? wq_lo : wk_lo;
#pragma unroll
        for (int j = 0; j < 4; ++j) {
            bf16 h, l;
            split2(vv[j], h, l);
            dh[base + j] = h;
            dl[base + j] = l;
        }
    }
}

// ---------------------------------------------------------------------------
// K3: projections. Block = 16 rows x ALL 512 cols (A strip read exactly once,
// no column re-tiling -> kills the 8x A over-fetch). 4 waves, wave = 16x128,
// acc[8]. Weights come from the packed [kb][col][32] layout (coalesced 1KB
// loads, L2-resident). z=0: q (split, packed [(b,h,kk,n)][32] out);
// z=1: k (same); z=2: v (plain bf16, vT[b*512+col][n]).
// ---------------------------------------------------------------------------
__global__ __launch_bounds__(256) void proj_kernel(
    const bf16* __restrict__ c_hi, const bf16* __restrict__ c_lo,
    const bf16* __restrict__ exo_bf,
    const bf16* __restrict__ wq_hi, const bf16* __restrict__ wq_lo,
    const bf16* __restrict__ wk_hi, const bf16* __restrict__ wk_lo,
    const bf16* __restrict__ wv_bf,
    const float* __restrict__ bq, const float* __restrict__ bk,
    const float* __restrict__ bv,
    bf16* __restrict__ q_hi, bf16* __restrict__ q_lo,
    bf16* __restrict__ k_hi, bf16* __restrict__ k_lo,
    bf16* __restrict__ vT)
{
    int z = blockIdx.z;
    int lane = threadIdx.x & 63;
    int wave = threadIdx.x >> 6;
    int lr = lane & 15;
    int lq = lane >> 4;
    int row0 = blockIdx.x * 16;
    int colw = wave * 128;

    v4f acc[8] = {};
    if (z < 2) {
        const bf16* Wh = (z == 0) ? wq_hi : wk_hi;
        const bf16* Wl = (z == 0) ? wq_lo : wk_lo;
        const bf16* xh = c_hi + (size_t)(row0 + lr) * DD + lq * 8;
        const bf16* xl = c_lo + (size_t)(row0 + lr) * DD + lq * 8;
        for (int d0 = 0; d0 < DD; d0 += 32) {
            v8s ah = *(const v8s*)(xh + d0);
            v8s al = *(const v8s*)(xl + d0);
            size_t wb = ((size_t)(d0 >> 5) * DD + colw) * 32 + lr * 32 + lq * 8;
#pragma unroll
            for (int t = 0; t < 8; ++t) {
                v8s bh = *(const v8s*)(Wh + wb + (size_t)t * 16 * 32);
                v8s bl = *(const v8s*)(Wl + wb + (size_t)t * 16 * 32);
                acc[t] = __builtin_amdgcn_mfma_f32_16x16x32_bf16(ah, bh, acc[t], 0, 0, 0);
                acc[t] = __builtin_amdgcn_mfma_f32_16x16x32_bf16(al, bh, acc[t], 0, 0, 0);
                acc[t] = __builtin_amdgcn_mfma_f32_16x16x32_bf16(ah, bl, acc[t], 0, 0, 0);
            }
        }
        const float* bias = (z == 0) ? bq : bk;
        bf16* oh = (z == 0) ? q_hi : k_hi;
        bf16* ol = (z == 0) ? q_lo : k_lo;
#pragma unroll
        for (int t = 0; t < 8; ++t) {
            int col = colw + 16 * t + lr;
            float bvv = bias[col];
            int h   = col >> 6;
            int kk2 = (col >> 5) & 1;
            int j   = col & 31;
#pragma unroll
            for (int r = 0; r < 4; ++r) {
                int row = row0 + lq * 4 + r;
                int b_ = row >> 10, n_ = row & (NN - 1);
                size_t idx = ((((size_t)b_ * NHH + h) * 2 + kk2) * NN + n_) * 32 + j;
                float val = acc[t][r] + bvv;
                bf16 hh, ll;
                split2(val, hh, ll);
                oh[idx] = hh;
                ol[idx] = ll;
            }
        }
    } else {
        const bf16* xp = exo_bf + (size_t)(row0 + lr) * DD + lq * 8;
        for (int d0 = 0; d0 < DD; d0 += 32) {
            v8s a = *(const v8s*)(xp + d0);
            size_t wb = ((size_t)(d0 >> 5) * DD + colw) * 32 + lr * 32 + lq * 8;
#pragma unroll
            for (int t = 0; t < 8; ++t) {
                v8s b = *(const v8s*)(wv_bf + wb + (size_t)t * 16 * 32);
                acc[t] = __builtin_amdgcn_mfma_f32_16x16x32_bf16(a, b, acc[t], 0, 0, 0);
            }
        }
#pragma unroll
        for (int t = 0; t < 8; ++t) {
            int col = colw + 16 * t + lr;
            float bvv = bv[col];
#pragma unroll
            for (int r = 0; r < 4; ++r) {
                int row = row0 + lq * 4 + r;
                int b_ = row >> 10, n_ = row & (NN - 1);
                vT[((size_t)b_ * DD + col) * NN + n_] =
                    __float2bfloat16(acc[t][r] + bvv);
            }
        }
    }
}

// ---------------------------------------------------------------------------
// K4: FUSED attention: scores (split 3-MFMA) -> register softmax -> *adj ->
// dist (nt f32 store) + bf16 P in LDS -> PV -> att. One block per
// (b, h, 16-row strip); wave w: QK^T cols [256w,256w+256), PV out cols
// [16w,16w+16) over full k. LDS = 33.5 KB -> 4 blocks/CU.
// q/k are in the packed [(b,h,kk,n)][32] layout (coalesced 1KB loads).
// ---------------------------------------------------------------------------
__global__ __launch_bounds__(256, 4) void attn_fused_kernel(
    const bf16* __restrict__ q_hi, const bf16* __restrict__ q_lo,
    const bf16* __restrict__ k_hi, const bf16* __restrict__ k_lo,
    const float* __restrict__ adj, const bf16* __restrict__ vT,
    float* __restrict__ dist, float* __restrict__ att)
{
    __shared__ __align__(16) short Pb[16][1032];  // bf16 P, +8 pad vs b128 bank conflicts
    __shared__ float redmx[4][16];
    __shared__ float redsm[4][16];

    int i0 = blockIdx.x * 16;
    int h  = blockIdx.y;
    int b  = blockIdx.z;
    int lane = threadIdx.x & 63;
    int wave = threadIdx.x >> 6;
    int lr = lane & 15, lq = lane >> 4;

    const size_t bh2 = (((size_t)b * NHH) + h) * 2;
    const bf16* qhp = q_hi + (bh2 * NN + i0 + lr) * 32 + lq * 8;
    const bf16* qlp = q_lo + (bh2 * NN + i0 + lr) * 32 + lq * 8;
    const bf16* khp = k_hi + bh2 * NN * 32 + lq * 8;
    const bf16* klp = k_lo + bh2 * NN * 32 + lq * 8;

    // ---- QK^T: acc[t][r] = S[row=lq*4+r][col=256*wave+16t+lr] (unscaled)
    v4f acc[16] = {};
#pragma unroll
    for (int kk = 0; kk < 2; ++kk) {
        v8s ah = *(const v8s*)(qhp + (size_t)kk * NN * 32);
        v8s al = *(const v8s*)(qlp + (size_t)kk * NN * 32);
#pragma unroll
        for (int t = 0; t < 16; ++t) {
            size_t off = (size_t)(kk * NN + wave * 256 + t * 16 + lr) * 32;
            v8s bh = *(const v8s*)(khp + off);
            v8s bl = *(const v8s*)(klp + off);
            acc[t] = __builtin_amdgcn_mfma_f32_16x16x32_bf16(ah, bh, acc[t], 0, 0, 0);
            acc[t] = __builtin_amdgcn_mfma_f32_16x16x32_bf16(al, bh, acc[t], 0, 0, 0);
            acc[t] = __builtin_amdgcn_mfma_f32_16x16x32_bf16(ah, bl, acc[t], 0, 0, 0);
        }
    }

    // ---- row max: in-lane over t, shfl_xor over the 16-lane lr group,
    //      then cross-wave via LDS.
    float mx[4];
#pragma unroll
    for (int r = 0; r < 4; ++r) {
        float m = acc[0][r];
#pragma unroll
        for (int t = 1; t < 16; ++t) m = fmaxf(m, acc[t][r]);
#pragma unroll
        for (int o = 8; o; o >>= 1) m = fmaxf(m, __shfl_xor(m, o, 64));
        mx[r] = m;
    }
    if (lr == 0) {
#pragma unroll
        for (int r = 0; r < 4; ++r) redmx[wave][lq * 4 + r] = mx[r];
    }
    __syncthreads();
#pragma unroll
    for (int r = 0; r < 4; ++r) {
        float m = fmaxf(fmaxf(redmx[0][lq * 4 + r], redmx[1][lq * 4 + r]),
                        fmaxf(redmx[2][lq * 4 + r], redmx[3][lq * 4 + r]));
        mx[r] = m;
    }

    // ---- exp (in place) + row sum (same two-level reduction)
    const float scale = 0.04419417382415922f;  // 1/sqrt(512)
    float sum_[4] = {0.0f, 0.0f, 0.0f, 0.0f};
#pragma unroll
    for (int t = 0; t < 16; ++t) {
#pragma unroll
        for (int r = 0; r < 4; ++r) {
            float e = __expf((acc[t][r] - mx[r]) * scale);
            acc[t][r] = e;
            sum_[r] += e;
        }
    }
#pragma unroll
    for (int r = 0; r < 4; ++r) {
#pragma unroll
        for (int o = 8; o; o >>= 1) sum_[r] += __shfl_xor(sum_[r], o, 64);
    }
    if (lr == 0) {
#pragma unroll
        for (int r = 0; r < 4; ++r) redsm[wave][lq * 4 + r] = sum_[r];
    }
    __syncthreads();
    float inv[4];
#pragma unroll
    for (int r = 0; r < 4; ++r) {
        float s = redsm[0][lq * 4 + r] + redsm[1][lq * 4 + r] +
                  redsm[2][lq * 4 + r] + redsm[3][lq * 4 + r];
        inv[r] = 1.0f / s;
    }

    // ---- dist = softmax * adj (nt store, never re-read) + bf16 P into LDS
#pragma unroll
    for (int t = 0; t < 16; ++t) {
        int col = wave * 256 + t * 16 + lr;
#pragma unroll
        for (int r = 0; r < 4; ++r) {
            int row = lq * 4 + r;
            int gi = i0 + row;
            float dv = acc[t][r] * inv[r] * adj[(size_t)gi * NN + col];
            __builtin_nontemporal_store(
                dv, dist + ((((size_t)b * NHH + h) * NN) + gi) * NN + col);
            Pb[row][col] = f2bf_bits(dv);
        }
    }
    __syncthreads();

    // ---- PV: wave w computes att cols [16w,16w+16) over full k=1024
    const bf16* vb = vT + ((size_t)b * DD + h * DH + wave * 16 + lr) * NN + lq * 8;
    v4f acc2 = {};
    for (int m0 = 0; m0 < NN; m0 += 32) {
        v8s a  = *(const v8s*)(&Pb[lr][m0 + lq * 8]);
        v8s bb = *(const v8s*)(vb + m0);
        acc2 = __builtin_amdgcn_mfma_f32_16x16x32_bf16(a, bb, acc2, 0, 0, 0);
    }
#pragma unroll
    for (int r = 0; r < 4; ++r) {
        int row = i0 + lq * 4 + r;
        __builtin_nontemporal_store(
            acc2[r], att + ((size_t)b * NN + row) * DD + h * DH + wave * 16 + lr);
    }
}

// ---------------------------------------------------------------------------
extern "C" void kernel_launch(void* const* d_in, const int* in_sizes, int n_in,
                              void* d_out, int out_size, void* d_ws, size_t ws_size,
                              hipStream_t stream)
{
    const float* user_exo = (const float*)d_in[0];
    const float* exo      = (const float*)d_in[1];
    const float* adj      = (const float*)d_in[2];
    const float* Wq       = (const float*)d_in[3];
    const float* bq       = (const float*)d_in[4];
    const float* Wk       = (const float*)d_in[5];
    const float* bk       = (const float*)d_in[6];
    const float* Wv       = (const float*)d_in[7];
    const float* bv       = (const float*)d_in[8];
    const float* gamma    = (const float*)d_in[9];
    const float* beta     = (const float*)d_in[10];

    float* att  = (float*)d_out;                     // [4,1024,512] f32
    float* dist = att + (size_t)BB * NN * DD;        // [4,8,1024,1024] f32

    const size_t NE = (size_t)BB * NN * DD;          // 2M elems
    const size_t WE = (size_t)DD * DD;               // 256K elems
    bf16* p = (bf16*)d_ws;
    bf16* c_hi   = p; p += NE;
    bf16* c_lo   = p; p += NE;
    bf16* exo_bf = p; p += NE;
    bf16* q_hi   = p; p += NE;                       // packed [(b,h,kk,n)][32]
    bf16* q_lo   = p; p += NE;
    bf16* k_hi   = p; p += NE;
    bf16* k_lo   = p; p += NE;
    bf16* vT     = p; p += NE;                       // [4,512,1024]
    bf16* wq_hi  = p; p += WE;                       // packed [kb][col][32]
    bf16* wq_lo  = p; p += WE;
    bf16* wk_hi  = p; p += WE;
    bf16* wk_lo  = p; p += WE;
    bf16* wv_bf  = p; p += WE;

    ln_split_kernel<<<BB * NN, 256, 0, stream>>>(user_exo, gamma, beta, c_hi, c_lo);
    convert_kernel<<<dim3((BB * NN * DD / 4 + 255) / 256, 1, 4), 256, 0, stream>>>(
        exo, Wq, Wk, Wv, exo_bf, wq_hi, wq_lo, wk_hi, wk_lo, wv_bf);
    proj_kernel<<<dim3(BB * NN / 16, 1, 3), 256, 0, stream>>>(
        c_hi, c_lo, exo_bf, wq_hi, wq_lo, wk_hi, wk_lo, wv_bf,
        bq, bk, bv, q_hi, q_lo, k_hi, k_lo, vT);
    attn_fused_kernel<<<dim3(NN / 16, NHH, BB), 256, 0, stream>>>(
        q_hi, q_lo, k_hi, k_lo, adj, vT, dist, att);
}